// Round 14
// baseline (1718.701 us; speedup 1.0000x reference)
//
#include <hip/hip_runtime.h>
#include <hip/hip_bf16.h>

#define T_ 1024
#define B_ 64
#define H_ 128
#define G_ 512   // 4*H
#define E_ 128
#define V_ 32
#define N_ 8

// ---- cross-lane helpers (compile-time controls) ---------------------------
template<int CTRL>
__device__ __forceinline__ float dppf(float x) {
    return __int_as_float(__builtin_amdgcn_update_dpp(0, __float_as_int(x), CTRL, 0xF, 0xF, true));
}
template<int CTRL>
__device__ __forceinline__ int dppi(int x) {
    return __builtin_amdgcn_update_dpp(0, x, CTRL, 0xF, 0xF, true);
}
template<int OFF>
__device__ __forceinline__ float swzf(float x) {
    return __int_as_float(__builtin_amdgcn_ds_swizzle(__float_as_int(x), OFF));
}
template<int OFF>
__device__ __forceinline__ int swzi(int x) {
    return __builtin_amdgcn_ds_swizzle(x, OFF);
}
// DPP ctrl constants: quad_perm[a,b,c,d] = a|b<<2|c<<4|d<<6
#define QP_XOR1 0xB1   // [1,0,3,2]
#define QP_XOR2 0x4E   // [2,3,0,1]
#define QP_BC0  0x00
#define QP_BC1  0x55
#define QP_BC2  0xAA
#define QP_BC3  0xFF
#define ROW_ROR8 0x128 // row_ror:8 == xor8 within 16-row (for sums)
// ds_swizzle BitMode: (xor<<10)|(or<<5)|and
#define SWZ_XOR4  0x101F
#define SWZ_XOR16 0x401F

// W residency via explicit AGPR pin (proven r8/r13: only mechanism that
// holds W). RD = non-volatile v_accvgpr_read (schedulable, r13).
#define RD(d, s) asm("v_accvgpr_read_b32 %0, %1" : "=v"(d) : "a"(s))
#define PIN8A(A, b_) asm volatile("" : "+a"(A[(b_)+0]), "+a"(A[(b_)+1]), \
    "+a"(A[(b_)+2]), "+a"(A[(b_)+3]), "+a"(A[(b_)+4]), "+a"(A[(b_)+5]), \
    "+a"(A[(b_)+6]), "+a"(A[(b_)+7]))

// ---------------------------------------------------------------------------
// K0: proj[dir][v][g] = b_dir[g] + sum_e W_ih_dir[g][e] * emb[v][e]
// ---------------------------------------------------------------------------
__global__ __launch_bounds__(512) void proj_kernel(
    const float* __restrict__ emb,
    const float* __restrict__ Wih_f, const float* __restrict__ b_f,
    const float* __restrict__ Wih_b, const float* __restrict__ b_b,
    float* __restrict__ proj)
{
    int wg  = blockIdx.x;
    int dir = wg >> 5;
    int v   = wg & 31;
    const float* W    = dir ? Wih_b : Wih_f;
    const float* bias = dir ? b_b   : b_f;
    int tid = threadIdx.x;

    __shared__ float4 e_l[E_ / 4];
    if (tid < E_ / 4) e_l[tid] = ((const float4*)(emb + (size_t)v * E_))[tid];
    __syncthreads();

    float acc = bias[tid];
    const float4* wr = (const float4*)(W + (size_t)tid * E_);
#pragma unroll
    for (int k = 0; k < 32; ++k) {
        float4 wv = wr[k], ev = e_l[k];
        acc += wv.x * ev.x;
        acc += wv.y * ev.y;
        acc += wv.z * ev.z;
        acc += wv.w * ev.w;
    }
    proj[((size_t)dir * V_ + v) * G_ + tid] = acc;
}

// ---------------------------------------------------------------------------
// K1: per-(dir,batch) LSTM chain + fused FC.  [NEW LAYOUT, r13's AGPR pin]
// grid 128, block 1024. Thread (j=tid>>3, q=tid&7) owns ALL 4 gate rows of
// unit j over h-chunk q (16 floats): wreg[4][16] -> 64 AGPRs.
// vs r13: h-reads halve (4x ds_read_b128), bank-perfect padded h layout
// ([8][20] floats: chunk q at 80q bytes -> 8 chunks tile all 32 banks),
// no W rotation, clean quad={i,f,g,o} gather. Reduce = 8-lane butterfly
// (xor1,xor2 DPP + xor4 swizzle) per gate; proj folded pre-reduce via
// exact 0/1 multipliers (added once per octet).
// ---------------------------------------------------------------------------
__global__ __launch_bounds__(1024)
__attribute__((amdgpu_waves_per_eu(4, 4)))
void lstm_kernel(
    const int*   __restrict__ x,
    const float* __restrict__ Whh_f, const float* __restrict__ Whh_b,
    const float* __restrict__ proj,   // [2][V][G]
    const float* __restrict__ fcW,    // [8][256]
    float* __restrict__ part)         // [2][T][B][8]
{
    int wg  = blockIdx.x;
    int dir = wg >> 6;
    int b   = wg & 63;
    int tid = threadIdx.x;
    int j   = tid >> 3;        // hidden unit 0..127
    int q   = tid & 7;         // h-chunk (16 floats)
    int g   = q & 3;           // gate this lane activates (i,f,g,o = 0..3)

    __shared__ union { int tok[T_]; char pad[83 * 1024]; } tu;  // 1-block/CU forcer
    __shared__ __align__(16) float hpad[2][8][20];  // chunk q at 80q bytes: bank-perfect

    tu.tok[tid] = x[(size_t)b * T_ + tid];
    if (tid < 320) ((float*)hpad)[tid] = 0.f;   // zero both buffers (+pads)

    int nw = tid >> 6;      // FC logit (waves 0-7)
    int e  = tid & 63;      // FC element pair
    float fw0 = 0.f, fw1 = 0.f;
    if (tid < 512) {
        fw0 = fcW[nw * 256 + dir * H_ + 2 * e];
        fw1 = fcW[nw * 256 + dir * H_ + 2 * e + 1];
    }
    int fc_off = ((2 * e) >> 4) * 20 + ((2 * e) & 15);  // float2 idx into hpad buf

    const float* Whh = dir ? Whh_b : Whh_f;

    // wreg[r][m] = W_hh[r*128+j][ q*16 + m ], m=0..15 — no rotation needed
    float wreg[4][16];
#pragma unroll
    for (int r = 0; r < 4; ++r) {
        const float4* wr = (const float4*)(Whh + (size_t)(r * H_ + j) * H_ + q * 16);
        float4 v0 = wr[0], v1 = wr[1], v2 = wr[2], v3 = wr[3];
        wreg[r][0]  = v0.x; wreg[r][1]  = v0.y; wreg[r][2]  = v0.z; wreg[r][3]  = v0.w;
        wreg[r][4]  = v1.x; wreg[r][5]  = v1.y; wreg[r][6]  = v1.z; wreg[r][7]  = v1.w;
        wreg[r][8]  = v2.x; wreg[r][9]  = v2.y; wreg[r][10] = v2.z; wreg[r][11] = v2.w;
        wreg[r][12] = v3.x; wreg[r][13] = v3.y; wreg[r][14] = v3.z; wreg[r][15] = v3.w;
    }
    PIN8A(wreg[0], 0); PIN8A(wreg[0], 8);
    PIN8A(wreg[1], 0); PIN8A(wreg[1], 8);
    PIN8A(wreg[2], 0); PIN8A(wreg[2], 8);
    PIN8A(wreg[3], 0); PIN8A(wreg[3], 8);
    asm volatile("" : "+v"(fw0), "+v"(fw1));

    const float* projd = proj + (size_t)dir * (V_ * G_);
    int gown = g * H_ + j;           // this lane's proj element (gate g, unit j)
    // exact one-per-octet proj fold: lane q==r adds pv to a_r (lanes 4-7 add 0)
    float m0 = (q == 0) ? 1.f : 0.f;
    float m1 = (q == 1) ? 1.f : 0.f;
    float m2 = (q == 2) ? 1.f : 0.f;
    float m3 = (q == 3) ? 1.f : 0.f;
    float cc = 0.f;
    __syncthreads();

    float pv_c = projd[tu.tok[dir ? (T_ - 1) : 0] * G_ + gown];

    // 16 RD+FMA for gate row r against hv0..hv3 (non-volatile, schedulable)
#define MVR(r, acc) { float t_; \
    RD(t_, wreg[r][0]);  acc += t_ * hv0.x; RD(t_, wreg[r][1]);  acc += t_ * hv0.y; \
    RD(t_, wreg[r][2]);  acc += t_ * hv0.z; RD(t_, wreg[r][3]);  acc += t_ * hv0.w; \
    RD(t_, wreg[r][4]);  acc += t_ * hv1.x; RD(t_, wreg[r][5]);  acc += t_ * hv1.y; \
    RD(t_, wreg[r][6]);  acc += t_ * hv1.z; RD(t_, wreg[r][7]);  acc += t_ * hv1.w; \
    RD(t_, wreg[r][8]);  acc += t_ * hv2.x; RD(t_, wreg[r][9]);  acc += t_ * hv2.y; \
    RD(t_, wreg[r][10]); acc += t_ * hv2.z; RD(t_, wreg[r][11]); acc += t_ * hv2.w; \
    RD(t_, wreg[r][12]); acc += t_ * hv3.x; RD(t_, wreg[r][13]); acc += t_ * hv3.y; \
    RD(t_, wreg[r][14]); acc += t_ * hv3.z; RD(t_, wreg[r][15]); acc += t_ * hv3.w; }

    int cur = 0;
    for (int t = 0; t < T_; ++t) {
        int tt = dir ? (T_ - 1 - t) : t;
        int tn = (t + 1 < T_) ? (t + 1) : t;
        float pv_n = projd[tu.tok[dir ? (T_ - 1 - tn) : tn] * G_ + gown];

        const float* hc = &hpad[cur][q][0];
        float4 hv0 = *(const float4*)(hc);
        float4 hv1 = *(const float4*)(hc + 4);
        float4 hv2 = *(const float4*)(hc + 8);
        float4 hv3 = *(const float4*)(hc + 12);

        float a0 = 0.f, a1 = 0.f, a2 = 0.f, a3 = 0.f;
        MVR(0, a0) MVR(1, a1) MVR(2, a2) MVR(3, a3)

        // fold proj (exactly once per gate across the octet)
        a0 += pv_c * m0; a1 += pv_c * m1; a2 += pv_c * m2; a3 += pv_c * m3;

        // 8-lane butterfly per gate: every lane ends with the full sums
        a0 += dppf<QP_XOR1>(a0); a0 += dppf<QP_XOR2>(a0); a0 += swzf<SWZ_XOR4>(a0);
        a1 += dppf<QP_XOR1>(a1); a1 += dppf<QP_XOR2>(a1); a1 += swzf<SWZ_XOR4>(a1);
        a2 += dppf<QP_XOR1>(a2); a2 += dppf<QP_XOR2>(a2); a2 += swzf<SWZ_XOR4>(a2);
        a3 += dppf<QP_XOR1>(a3); a3 += dppf<QP_XOR2>(a3); a3 += swzf<SWZ_XOR4>(a3);

        // lane activates its gate g = q&3; quad {0,1,2,3} = {i,f,g,o}
        float tot = (g == 0) ? a0 : (g == 1) ? a1 : (g == 2) ? a2 : a3;
        float act = (g == 2) ? tanhf(tot) : 1.f / (1.f + expf(-tot));

        float gi = dppf<QP_BC0>(act);
        float gf = dppf<QP_BC1>(act);
        float gg = dppf<QP_BC2>(act);
        float go = dppf<QP_BC3>(act);

        cc = gf * cc + gi * gg;
        float h = go * tanhf(cc);
        if (q == 0) hpad[cur ^ 1][j >> 4][j & 15] = h;
        __syncthreads();                   // single barrier per step

        // FC on waves 0-7: wave nw computes logit nw (2 FMA + butterfly)
        if (tid < 512) {
            float2 h2 = *(const float2*)&(((const float*)hpad[cur ^ 1])[fc_off]);
            float pa = fw0 * h2.x + fw1 * h2.y;
            pa += dppf<QP_XOR1>(pa);
            pa += dppf<QP_XOR2>(pa);
            pa += swzf<SWZ_XOR4>(pa);
            pa += dppf<ROW_ROR8>(pa);
            pa += swzf<SWZ_XOR16>(pa);
            float psum = pa + __int_as_float(__builtin_amdgcn_readlane(__float_as_int(pa), 32));
            if (e == 0) part[(((size_t)dir * T_ + tt) * B_ + b) * N_ + nw] = psum;
        }
        pv_c = pv_n;
        cur ^= 1;
    }
#undef MVR
}

// ---------------------------------------------------------------------------
// K2: Viterbi — round-3/6/7/10/11/12/13 alternating-layout version VERBATIM
// (passing, absmax 0 in six separate benches).
// ---------------------------------------------------------------------------
__global__ __launch_bounds__(64) void viterbi_kernel(
    const float* __restrict__ part,   // [2][T][B][8]
    const float* __restrict__ fc_b,
    const float* __restrict__ start_t,
    const float* __restrict__ end_t,
    const float* __restrict__ trans,  // [8][8]
    int* __restrict__ out)            // [B][T]
{
    int b = blockIdx.x;
    int l = threadIdx.x;
    int lo = l & 7, hi = l >> 3;

    __shared__ unsigned int hist_l[T_];

    float trA  = trans[lo * 8 + hi];   // style A: i=lo, j=hi
    float trB  = trans[hi * 8 + lo];   // style B: i=hi, j=lo
    float fcbA = fc_b[hi];
    float fcbB = fc_b[lo];
    const float* pf = part;
    const float* pb = part + (size_t)T_ * B_ * N_;

#define TSEL(ov, oi) { if ((ov) > v || ((ov) == v && (oi) < idx)) { v = (ov); idx = (oi); } }

#define VSTEPA(emval, tcur) { \
    float v = (score + trA) + (emval); int idx = lo; \
    { float ov = dppf<QP_XOR1>(v); int oi = dppi<QP_XOR1>(idx); TSEL(ov, oi) } \
    { float ov = dppf<QP_XOR2>(v); int oi = dppi<QP_XOR2>(idx); TSEL(ov, oi) } \
    { float ov = swzf<SWZ_XOR4>(v); int oi = swzi<SWZ_XOR4>(idx); TSEL(ov, oi) } \
    score = v; \
    unsigned pk = 0; \
    _Pragma("unroll") \
    for (int jj = 0; jj < 8; ++jj) \
        pk |= (unsigned)(__builtin_amdgcn_readlane(idx, 8 * jj) & 7) << (3 * jj); \
    if (l == 0) hist_l[tcur] = pk; }

#define VSTEPB(emval, tcur) { \
    float v = (score + trB) + (emval); int idx = hi; \
    { float ov = dppf<ROW_ROR8>(v); int oi = dppi<ROW_ROR8>(idx); TSEL(ov, oi) } \
    { float ov = swzf<SWZ_XOR16>(v); int oi = swzi<SWZ_XOR16>(idx); TSEL(ov, oi) } \
    { float ov = __shfl_xor(v, 32); int oi = __shfl_xor(idx, 32); TSEL(ov, oi) } \
    score = v; \
    unsigned pk = 0; \
    _Pragma("unroll") \
    for (int jj = 0; jj < 8; ++jj) \
        pk |= (unsigned)(__builtin_amdgcn_readlane(idx, jj) & 7) << (3 * jj); \
    if (l == 0) hist_l[tcur] = pk; }

#define LOADSUB(dst, ss) { \
    int t0_ = (ss) * 8; \
    _Pragma("unroll") \
    for (int p = 0; p < 8; ++p) { \
        int t_ = t0_ + p; \
        int jsel = (p & 1) ? hi : lo; \
        float fcbs = (p & 1) ? fcbA : fcbB; \
        size_t base = ((size_t)t_ * B_ + b) * N_ + jsel; \
        dst[p] = (pf[base] + pb[base]) + fcbs; } }

#define PROC8(arr, t0_) { \
    VSTEPB(arr[0], (t0_) + 0) VSTEPA(arr[1], (t0_) + 1) \
    VSTEPB(arr[2], (t0_) + 2) VSTEPA(arr[3], (t0_) + 3) \
    VSTEPB(arr[4], (t0_) + 4) VSTEPA(arr[5], (t0_) + 5) \
    VSTEPB(arr[6], (t0_) + 6) VSTEPA(arr[7], (t0_) + 7) }

    float emA[8], emB[8];
    float score;

    LOADSUB(emA, 0)
    LOADSUB(emB, 1)
    score = start_t[lo] + emA[0];
    VSTEPA(emA[1], 1) VSTEPB(emA[2], 2) VSTEPA(emA[3], 3) VSTEPB(emA[4], 4)
    VSTEPA(emA[5], 5) VSTEPB(emA[6], 6) VSTEPA(emA[7], 7)

    for (int s = 1; s < 127; s += 2) {
        LOADSUB(emA, s + 1)
        PROC8(emB, s * 8)
        LOADSUB(emB, s + 2)
        PROC8(emA, (s + 1) * 8)
    }
    PROC8(emB, 127 * 8)

    score += end_t[hi];
    int tag;
    {
        float v = score; int idx = hi;
        { float ov = dppf<ROW_ROR8>(v); int oi = dppi<ROW_ROR8>(idx); TSEL(ov, oi) }
        { float ov = swzf<SWZ_XOR16>(v); int oi = swzi<SWZ_XOR16>(idx); TSEL(ov, oi) }
        { float ov = __shfl_xor(v, 32); int oi = __shfl_xor(idx, 32); TSEL(ov, oi) }
        tag = idx;
    }
    if (l == 0) out[(size_t)b * T_ + (T_ - 1)] = tag;
    __syncthreads();

    for (int t0b = T_ - 16; t0b >= 0; t0b -= 16) {
        unsigned int pk[16];
#pragma unroll
        for (int qq = 0; qq < 16; ++qq) pk[qq] = hist_l[t0b + qq];
#pragma unroll
        for (int qq = 15; qq >= 0; --qq) {
            int t = t0b + qq;
            if (t >= 1) {
                tag = (pk[qq] >> (3 * tag)) & 7;
                if (l == 0) out[(size_t)b * T_ + t - 1] = tag;
            }
        }
    }
#undef TSEL
#undef VSTEPA
#undef VSTEPB
#undef LOADSUB
#undef PROC8
}

extern "C" void kernel_launch(void* const* d_in, const int* in_sizes, int n_in,
                              void* d_out, int out_size, void* d_ws, size_t ws_size,
                              hipStream_t stream) {
    (void)in_sizes; (void)n_in; (void)out_size; (void)ws_size;
    const int*   x      = (const int*)  d_in[0];
    const float* emb    = (const float*)d_in[1];
    const float* Wih_f  = (const float*)d_in[2];
    const float* Whh_f  = (const float*)d_in[3];
    const float* b_f    = (const float*)d_in[4];
    const float* Wih_b  = (const float*)d_in[5];
    const float* Whh_b  = (const float*)d_in[6];
    const float* b_b    = (const float*)d_in[7];
    const float* fcW    = (const float*)d_in[8];
    const float* fcb    = (const float*)d_in[9];
    const float* startt = (const float*)d_in[10];
    const float* endt   = (const float*)d_in[11];
    const float* trans  = (const float*)d_in[12];

    float* proj = (float*)d_ws;                    // 2*32*512 floats = 128 KB
    float* part = proj + 2 * V_ * G_;              // 2*1024*64*8 floats = 4 MB
    int*   out  = (int*)d_out;

    proj_kernel<<<64, 512, 0, stream>>>(emb, Wih_f, b_f, Wih_b, b_b, proj);
    lstm_kernel<<<128, 1024, 0, stream>>>(x, Whh_f, Whh_b, proj, fcW, part);
    viterbi_kernel<<<64, 64, 0, stream>>>(part, fcb, startt, endt, trans, out);
}

// Round 15
// 1140.245 us; speedup vs baseline: 1.5073x; 1.5073x over previous
//
#include <hip/hip_runtime.h>
#include <hip/hip_bf16.h>

#define T_ 1024
#define B_ 64
#define H_ 128
#define G_ 512   // 4*H
#define E_ 128
#define V_ 32
#define N_ 8

// ---- cross-lane helpers (compile-time controls) ---------------------------
template<int CTRL>
__device__ __forceinline__ float dppf(float x) {
    return __int_as_float(__builtin_amdgcn_update_dpp(0, __float_as_int(x), CTRL, 0xF, 0xF, true));
}
template<int CTRL>
__device__ __forceinline__ int dppi(int x) {
    return __builtin_amdgcn_update_dpp(0, x, CTRL, 0xF, 0xF, true);
}
template<int OFF>
__device__ __forceinline__ float swzf(float x) {
    return __int_as_float(__builtin_amdgcn_ds_swizzle(__float_as_int(x), OFF));
}
// DPP ctrl constants: quad_perm[a,b,c,d] = a|b<<2|c<<4|d<<6
#define QP_XOR1 0xB1   // [1,0,3,2]  == exact lane^1 exchange
#define QP_XOR2 0x4E   // [2,3,0,1]  == exact lane^2 exchange
#define QP_BC0  0x00
#define QP_BC1  0x55
#define QP_BC2  0xAA
#define QP_BC3  0xFF
#define ROW_ROR8 0x128 // row_ror:8 == exact lane^8 exchange within 16-row
// ds_swizzle BitMode: (xor<<10)|(or<<5)|and
#define SWZ_XOR4  0x101F
#define SWZ_XOR16 0x401F

// ---------------------------------------------------------------------------
// K0: proj[dir][v][g] = b_dir[g] + sum_e W_ih_dir[g][e] * emb[v][e]
// (verbatim from round 12 — passing)
// ---------------------------------------------------------------------------
__global__ __launch_bounds__(512) void proj_kernel(
    const float* __restrict__ emb,
    const float* __restrict__ Wih_f, const float* __restrict__ b_f,
    const float* __restrict__ Wih_b, const float* __restrict__ b_b,
    float* __restrict__ proj)
{
    int wg  = blockIdx.x;
    int dir = wg >> 5;
    int v   = wg & 31;
    const float* W    = dir ? Wih_b : Wih_f;
    const float* bias = dir ? b_b   : b_f;
    int tid = threadIdx.x;

    __shared__ float4 e_l[E_ / 4];
    if (tid < E_ / 4) e_l[tid] = ((const float4*)(emb + (size_t)v * E_))[tid];
    __syncthreads();

    float acc = bias[tid];
    const float4* wr = (const float4*)(W + (size_t)tid * E_);
#pragma unroll
    for (int k = 0; k < 32; ++k) {
        float4 wv = wr[k], ev = e_l[k];
        acc += wv.x * ev.x;
        acc += wv.y * ev.y;
        acc += wv.z * ev.z;
        acc += wv.w * ev.w;
    }
    proj[((size_t)dir * V_ + v) * G_ + tid] = acc;
}

// ---------------------------------------------------------------------------
// K1: per-(dir,batch) LSTM chain + fused FC — ROUND-12 VERBATIM (passing,
// 1020us; best of 14 rounds). L2-bound on compiler W-streaming; resident-W
// variants (r8/11/13/14) all regressed on accvgpr-read tax + lockstep stalls.
// ---------------------------------------------------------------------------
__global__ __launch_bounds__(1024)
__attribute__((amdgpu_waves_per_eu(4, 4)))
void lstm_kernel(
    const int*   __restrict__ x,
    const float* __restrict__ Whh_f, const float* __restrict__ Whh_b,
    const float* __restrict__ proj,   // [2][V][G]
    const float* __restrict__ fcW,    // [8][256]
    float* __restrict__ part)         // [2][T][B][8]
{
    int wg  = blockIdx.x;
    int dir = wg >> 6;
    int b   = wg & 63;
    int tid = threadIdx.x;
    int j   = tid >> 3;        // 0..127
    int q   = tid & 7;
    int p   = q & 1;           // gate pair -> rows {2p, 2p+1}
    int c   = q >> 1;          // h-chunk 0..3
    int which = c & 1;         // own gate within pair
    int gate_own = 2 * p + which;   // quad positions {0,1,2,3} -> gates {0,2,1,3}

    __shared__ union { int tok[T_]; char pad[83 * 1024]; } tu;  // 1-block/CU forcer
    __shared__ float4 hb4[2][H_ / 4];   // double-buffered h

    tu.tok[tid] = x[(size_t)b * T_ + tid];
    if (tid < H_) ((float*)hb4[0])[tid] = 0.f;

    int nw = tid >> 6;      // FC logit (waves 0-7)
    int e  = tid & 63;      // FC element pair
    float fw0 = 0.f, fw1 = 0.f;
    if (tid < 512) {
        fw0 = fcW[nw * 256 + dir * H_ + 2 * e];
        fw1 = fcW[nw * 256 + dir * H_ + 2 * e + 1];
    }

    const float* Whh = dir ? Whh_b : Whh_f;

    float4 w0[8], w1[8];
    {
        const float4* wr0 = (const float4*)(Whh + (size_t)((2 * p) * H_ + j) * H_ + c * 32);
        const float4* wr1 = (const float4*)(Whh + (size_t)((2 * p + 1) * H_ + j) * H_ + c * 32);
#pragma unroll
        for (int k = 0; k < 8; ++k) {
            w0[k] = wr0[(k + 2 * c) & 7];
            w1[k] = wr1[(k + 2 * c) & 7];
        }
    }
#pragma unroll
    for (int k = 0; k < 8; ++k) {
        asm volatile("" : "+v"(w0[k].x), "+v"(w0[k].y), "+v"(w0[k].z), "+v"(w0[k].w));
        asm volatile("" : "+v"(w1[k].x), "+v"(w1[k].y), "+v"(w1[k].z), "+v"(w1[k].w));
    }
    asm volatile("" : "+v"(fw0), "+v"(fw1));

    const float* projd = proj + (size_t)dir * (V_ * G_);
    int gown = gate_own * H_ + j;
    float cc = 0.f;
    __syncthreads();

    float pv_c = projd[tu.tok[dir ? (T_ - 1) : 0] * G_ + gown];

    int cur = 0;
    for (int t = 0; t < T_; ++t) {
        int tt = dir ? (T_ - 1 - t) : t;
        int tn = (t + 1 < T_) ? (t + 1) : t;
        float pv_n = projd[tu.tok[dir ? (T_ - 1 - tn) : tn] * G_ + gown];

        const float4* hb = (const float4*)hb4[cur];
        float a0 = 0.f, a1 = 0.f;
#pragma unroll
        for (int k = 0; k < 8; ++k) {
            float4 hv = hb[c * 8 + ((k + 2 * c) & 7)];
            float4 u0 = w0[k], u1 = w1[k];
            a0 += u0.x * hv.x; a0 += u0.y * hv.y; a0 += u0.z * hv.z; a0 += u0.w * hv.w;
            a1 += u1.x * hv.x; a1 += u1.y * hv.y; a1 += u1.z * hv.z; a1 += u1.w * hv.w;
        }
        a0 += dppf<QP_XOR2>(a0);
        a1 += dppf<QP_XOR2>(a1);
        a0 += swzf<SWZ_XOR4>(a0);
        a1 += swzf<SWZ_XOR4>(a1);

        float tot = which ? a1 : a0;
        tot += pv_c;
        float act = (gate_own == 2) ? tanhf(tot) : 1.f / (1.f + expf(-tot));

        float gi = dppf<QP_BC0>(act);
        float gg = dppf<QP_BC1>(act);
        float gf = dppf<QP_BC2>(act);
        float go = dppf<QP_BC3>(act);

        cc = gf * cc + gi * gg;
        float h = go * tanhf(cc);
        if (q == 0) ((float*)hb4[cur ^ 1])[j] = h;
        __syncthreads();                   // single barrier per step

        if (tid < 512) {
            float2 h2 = ((const float2*)hb4[cur ^ 1])[e];
            float pa = fw0 * h2.x + fw1 * h2.y;
            pa += dppf<QP_XOR1>(pa);
            pa += dppf<QP_XOR2>(pa);
            pa += swzf<SWZ_XOR4>(pa);
            pa += dppf<ROW_ROR8>(pa);
            pa += swzf<SWZ_XOR16>(pa);
            float psum = pa + __int_as_float(__builtin_amdgcn_readlane(__float_as_int(pa), 32));
            if (e == 0) part[(((size_t)dir * T_ + tt) * B_ + b) * N_ + nw] = psum;
        }
        pv_c = pv_n;
        cur ^= 1;
    }
}

// ---------------------------------------------------------------------------
// K2: Viterbi — REPLICATED-SCORE, ALL-DPP chain (no ds_swizzle/bpermute on
// the serial path). State index j lives on lane bits {0,1,3} so every
// exchange is an exact XOR with a DPP encoding: xor1/xor2 = quad_perm,
// xor8 = row_ror:8 (all three proven-exact in passing kernels). Each lane
// holds all 8 scores; per step: 16 adds + 7-cmp argmax tree (first-index
// ties, same tree as passing rounds) + 7-DPP/14-select allgather + DPP
// OR-tree hist. Em loads & backtrack keep the proven r3 skeleton.
// ---------------------------------------------------------------------------
__global__ __launch_bounds__(64) void viterbi_kernel(
    const float* __restrict__ part,   // [2][T][B][8]
    const float* __restrict__ fc_b,
    const float* __restrict__ start_t,
    const float* __restrict__ end_t,
    const float* __restrict__ trans,  // [8][8]
    int* __restrict__ out)            // [B][T]
{
    int b = blockIdx.x;
    int l = threadIdx.x;
    // j = b0 + 2*b1 + 4*b3 of the lane id (bits {0,1,3} = DPP-xor-able set)
    int j = (l & 3) | ((l >> 1) & 4);
    bool b0c = (l & 1) != 0;
    bool b1c = (l & 2) != 0;
    bool b3c = (l & 8) != 0;
    int sh3 = 3 * j;

    __shared__ unsigned int hist_l[T_];

    float tr[8];
#pragma unroll
    for (int i = 0; i < 8; ++i) tr[i] = trans[i * 8 + j];   // column j
    float endt_r[8];
#pragma unroll
    for (int i = 0; i < 8; ++i) endt_r[i] = end_t[i];
    float fcb = fc_b[j];
    const float* pf = part;
    const float* pb = part + (size_t)T_ * B_ * N_;

    float s[8];

    // Allgather: input xx = new score for state j(l); output s[0..7] = all 8
    // new scores, identical in every lane. Derivation (checked level-by-level):
    //  A0/A1 = f(b0=0/1, b1=own, b3=own); B_{i1 i0} = f(b1=i1, b0=i0, b3=own);
    //  s[i0+2*i1+4*i2] = (own b3 == i2) ? B : xor8(B).
#define SHARE(xx) { \
    float y_ = dppf<QP_XOR1>(xx); \
    float A0 = b0c ? y_ : (xx); float A1 = b0c ? (xx) : y_; \
    float A0x = dppf<QP_XOR2>(A0); float A1x = dppf<QP_XOR2>(A1); \
    float B00 = b1c ? A0x : A0; float B10 = b1c ? A0 : A0x; \
    float B01 = b1c ? A1x : A1; float B11 = b1c ? A1 : A1x; \
    float C00 = dppf<ROW_ROR8>(B00); float C01 = dppf<ROW_ROR8>(B01); \
    float C10 = dppf<ROW_ROR8>(B10); float C11 = dppf<ROW_ROR8>(B11); \
    s[0] = b3c ? C00 : B00;  s[1] = b3c ? C01 : B01; \
    s[2] = b3c ? C10 : B10;  s[3] = b3c ? C11 : B11; \
    s[4] = b3c ? B00 : C00;  s[5] = b3c ? B01 : C01; \
    s[6] = b3c ? B10 : C10;  s[7] = b3c ? B11 : C11; }

#define VSTEP(emv, tcur) { \
    float v0 = (s[0] + tr[0]) + (emv); \
    float v1 = (s[1] + tr[1]) + (emv); \
    float v2 = (s[2] + tr[2]) + (emv); \
    float v3 = (s[3] + tr[3]) + (emv); \
    float v4 = (s[4] + tr[4]) + (emv); \
    float v5 = (s[5] + tr[5]) + (emv); \
    float v6 = (s[6] + tr[6]) + (emv); \
    float v7 = (s[7] + tr[7]) + (emv); \
    float va = (v1 > v0) ? v1 : v0;  int ia = (v1 > v0) ? 1 : 0; \
    float vb = (v3 > v2) ? v3 : v2;  int ib = (v3 > v2) ? 3 : 2; \
    float vc = (v5 > v4) ? v5 : v4;  int ic = (v5 > v4) ? 5 : 4; \
    float vd = (v7 > v6) ? v7 : v6;  int id_ = (v7 > v6) ? 7 : 6; \
    float ve = (vb > va) ? vb : va;  int ie = (vb > va) ? ib : ia; \
    float vf = (vd > vc) ? vd : vc;  int if_ = (vd > vc) ? id_ : ic; \
    float vg = (vf > ve) ? vf : ve;  int ig = (vf > ve) ? if_ : ie; \
    SHARE(vg) \
    unsigned pk = (unsigned)ig << sh3; \
    pk |= (unsigned)dppi<QP_XOR1>((int)pk); \
    pk |= (unsigned)dppi<QP_XOR2>((int)pk); \
    pk |= (unsigned)dppi<ROW_ROR8>((int)pk); \
    if (l == 0) hist_l[tcur] = pk; }

    // em loads for sub-block ss (8 steps): dst[p] = (pf+pb)+fcb at own j
#define LOADSUB(dst, ss) { \
    int t0_ = (ss) * 8; \
    _Pragma("unroll") \
    for (int p = 0; p < 8; ++p) { \
        size_t base = ((size_t)(t0_ + p) * B_ + b) * N_ + j; \
        dst[p] = (pf[base] + pb[base]) + fcb; } }

#define PROC8(arr, t0_) { \
    VSTEP(arr[0], (t0_) + 0) VSTEP(arr[1], (t0_) + 1) \
    VSTEP(arr[2], (t0_) + 2) VSTEP(arr[3], (t0_) + 3) \
    VSTEP(arr[4], (t0_) + 4) VSTEP(arr[5], (t0_) + 5) \
    VSTEP(arr[6], (t0_) + 6) VSTEP(arr[7], (t0_) + 7) }

    float emA[8], emB[8];
    LOADSUB(emA, 0)
    LOADSUB(emB, 1)

    // t=0 init: score0[j] = start_t[j] + em[0][j], then replicate
    {
        float x0 = start_t[j] + emA[0];
        SHARE(x0)
    }
    VSTEP(emA[1], 1) VSTEP(emA[2], 2) VSTEP(emA[3], 3) VSTEP(emA[4], 4)
    VSTEP(emA[5], 5) VSTEP(emA[6], 6) VSTEP(emA[7], 7)

    for (int ss = 1; ss < 127; ss += 2) {
        LOADSUB(emA, ss + 1)
        PROC8(emB, ss * 8)
        LOADSUB(emB, ss + 2)
        PROC8(emA, (ss + 1) * 8)
    }
    PROC8(emB, 127 * 8)

    // finalize: s[i] += end_t[i]; argmax (first-index ties) — no cross-lane
    int tag;
    {
        float v0 = s[0] + endt_r[0];
        float v1 = s[1] + endt_r[1];
        float v2 = s[2] + endt_r[2];
        float v3 = s[3] + endt_r[3];
        float v4 = s[4] + endt_r[4];
        float v5 = s[5] + endt_r[5];
        float v6 = s[6] + endt_r[6];
        float v7 = s[7] + endt_r[7];
        float va = (v1 > v0) ? v1 : v0;  int ia = (v1 > v0) ? 1 : 0;
        float vb = (v3 > v2) ? v3 : v2;  int ib = (v3 > v2) ? 3 : 2;
        float vc = (v5 > v4) ? v5 : v4;  int ic = (v5 > v4) ? 5 : 4;
        float vd = (v7 > v6) ? v7 : v6;  int id_ = (v7 > v6) ? 7 : 6;
        float ve = (vb > va) ? vb : va;  int ie = (vb > va) ? ib : ia;
        float vf = (vd > vc) ? vd : vc;  int if_ = (vd > vc) ? id_ : ic;
        tag = (vf > ve) ? if_ : ie;
    }
    if (l == 0) out[(size_t)b * T_ + (T_ - 1)] = tag;
    __syncthreads();

    // backtrack: prefetch 16 packed words -> serial chain is VALU-only
    for (int t0b = T_ - 16; t0b >= 0; t0b -= 16) {
        unsigned int pk[16];
#pragma unroll
        for (int qq = 0; qq < 16; ++qq) pk[qq] = hist_l[t0b + qq];
#pragma unroll
        for (int qq = 15; qq >= 0; --qq) {
            int t = t0b + qq;
            if (t >= 1) {
                tag = (pk[qq] >> (3 * tag)) & 7;
                if (l == 0) out[(size_t)b * T_ + t - 1] = tag;
            }
        }
    }
#undef SHARE
#undef VSTEP
#undef LOADSUB
#undef PROC8
}

extern "C" void kernel_launch(void* const* d_in, const int* in_sizes, int n_in,
                              void* d_out, int out_size, void* d_ws, size_t ws_size,
                              hipStream_t stream) {
    (void)in_sizes; (void)n_in; (void)out_size; (void)ws_size;
    const int*   x      = (const int*)  d_in[0];
    const float* emb    = (const float*)d_in[1];
    const float* Wih_f  = (const float*)d_in[2];
    const float* Whh_f  = (const float*)d_in[3];
    const float* b_f    = (const float*)d_in[4];
    const float* Wih_b  = (const float*)d_in[5];
    const float* Whh_b  = (const float*)d_in[6];
    const float* b_b    = (const float*)d_in[7];
    const float* fcW    = (const float*)d_in[8];
    const float* fcb    = (const float*)d_in[9];
    const float* startt = (const float*)d_in[10];
    const float* endt   = (const float*)d_in[11];
    const float* trans  = (const float*)d_in[12];

    float* proj = (float*)d_ws;                    // 2*32*512 floats = 128 KB
    float* part = proj + 2 * V_ * G_;              // 2*1024*64*8 floats = 4 MB
    int*   out  = (int*)d_out;

    proj_kernel<<<64, 512, 0, stream>>>(emb, Wih_f, b_f, Wih_b, b_b, proj);
    lstm_kernel<<<128, 1024, 0, stream>>>(x, Whh_f, Whh_b, proj, fcW, part);
    viterbi_kernel<<<64, 64, 0, stream>>>(part, fcb, startt, endt, trans, out);
}